// Round 12
// baseline (351.987 us; speedup 1.0000x reference)
//
#include <hip/hip_runtime.h>
#include <math.h>

#define F_IN 128
#define HID 64
#define NCLS 32
#define NEG 0.2f
#define NBKT 256          // nodes per bucket (dst >> 8)
#define CHUNK 8192        // edges per block in bucket passes

__device__ __forceinline__ void f4fma(float4& a, float s, const float4& w) {
    a.x = fmaf(s, w.x, a.x);
    a.y = fmaf(s, w.y, a.y);
    a.z = fmaf(s, w.z, a.z);
    a.w = fmaf(s, w.w, a.w);
}
// float -> bf16 (round to nearest even), bf16 -> float
__device__ __forceinline__ unsigned short f2bf(float f) {
    unsigned u = __float_as_uint(f);
    return (unsigned short)((u + 0x7FFFu + ((u >> 16) & 1u)) >> 16);
}

// =====================  CSR build: bucketed counting sort  =====================

__global__ __launch_bounds__(256) void zeroBuckets(int* __restrict__ bucketSize, int BK) {
    int i = blockIdx.x * 256 + threadIdx.x;
    if (i < BK) bucketSize[i] = 0;
}

__global__ __launch_bounds__(256) void bucketHist(const int* __restrict__ ei,
                                                  int Eorig, int Etot,
                                                  int* __restrict__ bucketSize, int BK) {
    __shared__ int h[512];
    int t = threadIdx.x;
    for (int j = t; j < BK; j += 256) h[j] = 0;
    __syncthreads();
    int base = blockIdx.x * CHUNK;
    int end = base + CHUNK < Etot ? base + CHUNK : Etot;
    for (int i = base + t; i < end; i += 256) {
        int dst = i < Eorig ? ei[Eorig + i] : i - Eorig;
        atomicAdd(&h[dst >> 8], 1);
    }
    __syncthreads();
    for (int j = t; j < BK; j += 256)
        if (h[j]) atomicAdd(&bucketSize[j], h[j]);
}

__global__ __launch_bounds__(256) void bucketScan(const int* __restrict__ bucketSize,
                                                  int* __restrict__ bucketStart,
                                                  int* __restrict__ bucketCursor,
                                                  int BK, int Etot) {
    __shared__ int sd[256];
    int t = threadIdx.x;
    int v0 = (2 * t     < BK) ? bucketSize[2 * t]     : 0;
    int v1 = (2 * t + 1 < BK) ? bucketSize[2 * t + 1] : 0;
    int ts = v0 + v1;
    sd[t] = ts;
    __syncthreads();
    for (int off = 1; off < 256; off <<= 1) {
        int x = (t >= off) ? sd[t - off] : 0;
        __syncthreads();
        sd[t] += x;
        __syncthreads();
    }
    int excl = sd[t] - ts;
    if (2 * t < BK)     { bucketStart[2 * t] = excl;          bucketCursor[2 * t] = excl; }
    if (2 * t + 1 < BK) { bucketStart[2 * t + 1] = excl + v0; bucketCursor[2 * t + 1] = excl + v0; }
    if (t == 255) bucketStart[BK] = Etot;
}

__global__ __launch_bounds__(256) void bucketScatter(const int* __restrict__ ei,
                                                     int Eorig, int Etot,
                                                     int* __restrict__ bucketCursor,
                                                     int2* __restrict__ pairs, int BK) {
    __shared__ int h[512], lbase[512], hcur[512];
    int t = threadIdx.x;
    for (int j = t; j < BK; j += 256) { h[j] = 0; hcur[j] = 0; }
    __syncthreads();
    int base = blockIdx.x * CHUNK;
    int end = base + CHUNK < Etot ? base + CHUNK : Etot;
    for (int i = base + t; i < end; i += 256) {
        int dst = i < Eorig ? ei[Eorig + i] : i - Eorig;
        atomicAdd(&h[dst >> 8], 1);
    }
    __syncthreads();
    for (int j = t; j < BK; j += 256)
        lbase[j] = h[j] ? atomicAdd(&bucketCursor[j], h[j]) : 0;
    __syncthreads();
    for (int i = base + t; i < end; i += 256) {
        int src, dst;
        if (i < Eorig) { src = ei[i]; dst = ei[Eorig + i]; }
        else           { src = dst = i - Eorig; }
        int b = dst >> 8;
        int off = atomicAdd(&hcur[b], 1);
        pairs[lbase[b] + off] = make_int2(src, dst);
    }
}

__global__ __launch_bounds__(256) void bucketCSR(const int2* __restrict__ pairs,
                                                 const int* __restrict__ bucketStart,
                                                 int* __restrict__ rowstart,
                                                 int* __restrict__ cnt,
                                                 int* __restrict__ srclist, int N) {
    __shared__ int c[256], cur[256];
    int t = threadIdx.x;
    int b = blockIdx.x;
    int lo = b * NBKT;
    int eb = bucketStart[b], ee = bucketStart[b + 1];
    c[t] = 0;
    __syncthreads();
    for (int i = eb + t; i < ee; i += 256)
        atomicAdd(&c[pairs[i].y - lo], 1);
    __syncthreads();
    cur[t] = c[t];
    __syncthreads();
    for (int off = 1; off < 256; off <<= 1) {
        int x = (t >= off) ? cur[t - off] : 0;
        __syncthreads();
        cur[t] += x;
        __syncthreads();
    }
    int excl = cur[t] - c[t];
    int node = lo + t;
    if (node < N) { rowstart[node] = eb + excl; cnt[node] = c[t]; }
    __syncthreads();
    cur[t] = excl;
    __syncthreads();
    for (int i = eb + t; i < ee; i += 256) {
        int2 pr = pairs[i];
        int pos = atomicAdd(&cur[pr.y - lo], 1);
        srclist[eb + pos] = pr.x;
    }
}

// =====================  dense transforms (LDS-staged W)  =====================
// transform1: 64 nodes x both matrices, K-tiled staging (49.4KB LDS).
// xl emitted bf16-packed, xr fp32.
__global__ __launch_bounds__(256) void transform1(const float* __restrict__ x,
                                                  const float* __restrict__ Wl,
                                                  const float* __restrict__ bl,
                                                  const float* __restrict__ Wr,
                                                  const float* __restrict__ br,
                                                  unsigned short* __restrict__ xlb,
                                                  float* __restrict__ xr, int N) {
    __shared__ float sWl[64 * HID];    // K-half of Wl
    __shared__ float sWr[64 * HID];
    __shared__ float sx[64][68];       // 64 nodes x 64k (half)
    int t = threadIdx.x;
    int nb = blockIdx.x * 64;
    int c4 = (t & 15) * 4;
    int slot = t >> 4;
    int maxnode = N - nb;

    float4 bl4 = *(const float4*)(bl + c4);
    float4 br4 = *(const float4*)(br + c4);
    float4 accl[4] = {bl4, bl4, bl4, bl4};
    float4 accr[4] = {br4, br4, br4, br4};

    for (int kt = 0; kt < 2; kt++) {
        if (kt) __syncthreads();
#pragma unroll
        for (int j = 0; j < 4; j++) {
            int f = t + j * 256;
            ((float4*)sWl)[f] = ((const float4*)Wl)[kt * 1024 + f];
            ((float4*)sWr)[f] = ((const float4*)Wr)[kt * 1024 + f];
            int node = f >> 4, kc = f & 15;
            float4 v = {0.f, 0.f, 0.f, 0.f};
            if (node < maxnode)
                v = ((const float4*)x)[(size_t)(nb + node) * 32 + kt * 16 + kc];
            *(float4*)&sx[node][kc * 4] = v;
        }
        __syncthreads();

#pragma unroll 4
        for (int k4 = 0; k4 < 16; k4++) {
            int k = k4 * 4;
            float4 wl0 = *(const float4*)&sWl[(k + 0) * HID + c4];
            float4 wl1 = *(const float4*)&sWl[(k + 1) * HID + c4];
            float4 wl2 = *(const float4*)&sWl[(k + 2) * HID + c4];
            float4 wl3 = *(const float4*)&sWl[(k + 3) * HID + c4];
            float4 wr0 = *(const float4*)&sWr[(k + 0) * HID + c4];
            float4 wr1 = *(const float4*)&sWr[(k + 1) * HID + c4];
            float4 wr2 = *(const float4*)&sWr[(k + 2) * HID + c4];
            float4 wr3 = *(const float4*)&sWr[(k + 3) * HID + c4];
#pragma unroll
            for (int j = 0; j < 4; j++) {
                float4 xv = *(const float4*)&sx[slot + j * 16][k];
                f4fma(accl[j], xv.x, wl0); f4fma(accr[j], xv.x, wr0);
                f4fma(accl[j], xv.y, wl1); f4fma(accr[j], xv.y, wr1);
                f4fma(accl[j], xv.z, wl2); f4fma(accr[j], xv.z, wr2);
                f4fma(accl[j], xv.w, wl3); f4fma(accr[j], xv.w, wr3);
            }
        }
    }
#pragma unroll
    for (int j = 0; j < 4; j++) {
        int g = nb + slot + j * 16;
        if (g < N) {
            ushort4 o;
            o.x = f2bf(accl[j].x); o.y = f2bf(accl[j].y);
            o.z = f2bf(accl[j].z); o.w = f2bf(accl[j].w);
            *(ushort4*)(xlb + (size_t)g * HID + c4) = o;
            *(float4*)(xr + (size_t)g * HID + c4) = accr[j];
        }
    }
}

// transform2: xl emitted bf16-packed (gather table), xr fp32. ReLU fused.
__global__ __launch_bounds__(256) void transform2(const float* __restrict__ h,
                                                  const float* __restrict__ Wl,
                                                  const float* __restrict__ bl,
                                                  const float* __restrict__ Wr,
                                                  const float* __restrict__ br,
                                                  unsigned short* __restrict__ xlb,
                                                  float* __restrict__ xr, int N) {
    __shared__ float sWl[HID * NCLS];
    __shared__ float sWr[HID * NCLS];
    __shared__ float sx[128][68];
    int t = threadIdx.x;
    int nb = blockIdx.x * 128;

#pragma unroll
    for (int j = 0; j < 2; j++) {
        int f = t + j * 256;
        ((float4*)sWl)[f] = ((const float4*)Wl)[f];
        ((float4*)sWr)[f] = ((const float4*)Wr)[f];
    }
    int maxf = (N - nb) * 16;
#pragma unroll
    for (int j = 0; j < 8; j++) {
        int f = t + j * 256;
        int node = f >> 4, kc = f & 15;
        float4 v = {0.f, 0.f, 0.f, 0.f};
        if (f < maxf) v = ((const float4*)(h + (size_t)nb * HID))[f];
        v.x = fmaxf(v.x, 0.f);
        v.y = fmaxf(v.y, 0.f);
        v.z = fmaxf(v.z, 0.f);
        v.w = fmaxf(v.w, 0.f);
        *(float4*)&sx[node][kc * 4] = v;
    }
    __syncthreads();

    int c4 = (t & 7) * 4;
    int slot = t >> 3;
    float4 bl4 = *(const float4*)(bl + c4);
    float4 br4 = *(const float4*)(br + c4);
    float4 accl[4] = {bl4, bl4, bl4, bl4};
    float4 accr[4] = {br4, br4, br4, br4};

#pragma unroll 4
    for (int k4 = 0; k4 < HID / 4; k4++) {
        int k = k4 * 4;
        float4 wl0 = *(const float4*)&sWl[(k + 0) * NCLS + c4];
        float4 wl1 = *(const float4*)&sWl[(k + 1) * NCLS + c4];
        float4 wl2 = *(const float4*)&sWl[(k + 2) * NCLS + c4];
        float4 wl3 = *(const float4*)&sWl[(k + 3) * NCLS + c4];
        float4 wr0 = *(const float4*)&sWr[(k + 0) * NCLS + c4];
        float4 wr1 = *(const float4*)&sWr[(k + 1) * NCLS + c4];
        float4 wr2 = *(const float4*)&sWr[(k + 2) * NCLS + c4];
        float4 wr3 = *(const float4*)&sWr[(k + 3) * NCLS + c4];
#pragma unroll
        for (int j = 0; j < 4; j++) {
            float4 xv = *(const float4*)&sx[slot + j * 32][k];
            f4fma(accl[j], xv.x, wl0); f4fma(accr[j], xv.x, wr0);
            f4fma(accl[j], xv.y, wl1); f4fma(accr[j], xv.y, wr1);
            f4fma(accl[j], xv.z, wl2); f4fma(accr[j], xv.z, wr2);
            f4fma(accl[j], xv.w, wl3); f4fma(accr[j], xv.w, wr3);
        }
    }
#pragma unroll
    for (int j = 0; j < 4; j++) {
        int g = nb + slot + j * 32;
        if (g < N) {
            ushort4 o;
            o.x = f2bf(accl[j].x); o.y = f2bf(accl[j].y);
            o.z = f2bf(accl[j].z); o.w = f2bf(accl[j].w);
            *(ushort4*)(xlb + (size_t)g * NCLS + c4) = o;
            *(float4*)(xr + (size_t)g * NCLS + c4) = accr[j];
        }
    }
}

// =====================  fused softmax aggregation v6  =====================
// One wave per node, 8 channels per lane (bf16 gather = one 16B load).
// LPQ = C/8 lanes per edge -> SLOTS = 64/LPQ edges per batch: butterfly is
// 3 stages (C=64) / 2 stages (C=32), amortized over 8/16 edges per batch.
// No max-subtraction (logits O(1), softmax shift-invariant). No atomics.
template <int C>
__global__ __launch_bounds__(256) void fusedAggB(const unsigned short* __restrict__ xlb,
                                                 const float* __restrict__ xr,
                                                 const float* __restrict__ att,
                                                 const int* __restrict__ rowstart,
                                                 const int* __restrict__ cnt,
                                                 const int* __restrict__ srclist,
                                                 const float* __restrict__ bias,
                                                 float* __restrict__ out, int N) {
    const int LPQ = C / 8;          // lanes per edge (8 or 4)
    const int SLOTS = 64 / LPQ;     // edges per batch (8 or 16)
    int wid = threadIdx.x >> 6;
    int lane = threadIdx.x & 63;
    int n = blockIdx.x * 4 + wid;
    if (n >= N) return;

    int slot = lane / LPQ;
    int pos = lane % LPQ;
    int c8 = pos * 8;

    float xr8[8], at8[8];
    *(float4*)&xr8[0] = *(const float4*)(xr + (size_t)n * C + c8);
    *(float4*)&xr8[4] = *(const float4*)(xr + (size_t)n * C + c8 + 4);
    *(float4*)&at8[0] = *(const float4*)(att + c8);
    *(float4*)&at8[4] = *(const float4*)(att + c8 + 4);

    int row = rowstart[n];
    int deg = cnt[n];

    float s = 0.f;
    float acc[8] = {0.f, 0.f, 0.f, 0.f, 0.f, 0.f, 0.f, 0.f};

    for (int cb = 0; cb < deg; cb += 64) {
        int len = deg - cb; if (len > 64) len = 64;
        int li = lane < len ? lane : len - 1;
        int srcreg = srclist[row + cb + li];
        int nbatch = (len + SLOTS - 1) / SLOTS;
#pragma unroll 2
        for (int b = 0; b < nbatch; b++) {
            int eidx = b * SLOTS + slot;
            int src = __shfl(srcreg, eidx, 64);
            uint4 q = *(const uint4*)(xlb + (size_t)src * C + c8);  // 8 bf16
            float v[8];
            v[0] = __uint_as_float(q.x << 16);
            v[1] = __uint_as_float(q.x & 0xffff0000u);
            v[2] = __uint_as_float(q.y << 16);
            v[3] = __uint_as_float(q.y & 0xffff0000u);
            v[4] = __uint_as_float(q.z << 16);
            v[5] = __uint_as_float(q.z & 0xffff0000u);
            v[6] = __uint_as_float(q.w << 16);
            v[7] = __uint_as_float(q.w & 0xffff0000u);
            float p = 0.f;
#pragma unroll
            for (int c = 0; c < 8; c++) {
                float u = v[c] + xr8[c];
                u = fmaxf(u, NEG * u);           // leaky_relu
                p = fmaf(u, at8[c], p);
            }
#pragma unroll
            for (int o = 1; o < LPQ; o <<= 1) p += __shfl_xor(p, o, 64);
            float w = (eidx < len) ? __expf(p) : 0.f;
            s += w;
#pragma unroll
            for (int c = 0; c < 8; c++) acc[c] = fmaf(w, v[c], acc[c]);
        }
    }
    // combine across slots (butterfly over slot bits); lanes within a slot
    // hold identical s, so summing over slot bits counts each edge once.
#pragma unroll
    for (int o = LPQ; o < 64; o <<= 1) {
#pragma unroll
        for (int c = 0; c < 8; c++) acc[c] += __shfl_xor(acc[c], o, 64);
        s += __shfl_xor(s, o, 64);
    }
    if (lane < LPQ) {
        float bi8[8];
        *(float4*)&bi8[0] = *(const float4*)(bias + c8);
        *(float4*)&bi8[4] = *(const float4*)(bias + c8 + 4);
        float inv = 1.f / (s + 1e-16f);
        float o8[8];
#pragma unroll
        for (int c = 0; c < 8; c++) o8[c] = acc[c] * inv + bi8[c];
        *(float4*)(out + (size_t)n * C + c8)     = *(float4*)&o8[0];
        *(float4*)(out + (size_t)n * C + c8 + 4) = *(float4*)&o8[4];
    }
}

extern "C" void kernel_launch(void* const* d_in, const int* in_sizes, int n_in,
                              void* d_out, int out_size, void* d_ws, size_t ws_size,
                              hipStream_t stream) {
    const float* x     = (const float*)d_in[0];
    const int*   ei    = (const int*)d_in[1];
    const float* W1l   = (const float*)d_in[2];
    const float* b1l   = (const float*)d_in[3];
    const float* W1r   = (const float*)d_in[4];
    const float* b1r   = (const float*)d_in[5];
    const float* att1  = (const float*)d_in[6];
    const float* bias1 = (const float*)d_in[7];
    const float* W2l   = (const float*)d_in[8];
    const float* b2l   = (const float*)d_in[9];
    const float* W2r   = (const float*)d_in[10];
    const float* b2r   = (const float*)d_in[11];
    const float* att2  = (const float*)d_in[12];
    const float* bias2 = (const float*)d_in[13];
    float* out = (float*)d_out;

    int N     = in_sizes[0] / F_IN;   // 100000
    int Eorig = in_sizes[1] / 2;      // 1600000
    int Etot  = Eorig + N;
    int BK    = (N + NBKT - 1) / NBKT;   // 391 buckets (<=512)

    char* p = (char*)d_ws;
    auto alloc = [&](size_t bytes) { void* r = (void*)p; p += (bytes + 255) & ~(size_t)255; return r; };
    unsigned short* xl1b = (unsigned short*)alloc((size_t)N * HID * 2);   // bf16 table L1
    float* xr1     = (float*)alloc((size_t)N * HID * 4);
    float* h       = (float*)alloc((size_t)N * HID * 4);
    unsigned short* xl2b = (unsigned short*)alloc((size_t)N * NCLS * 2);  // bf16 table L2
    float* xr2     = (float*)alloc((size_t)N * NCLS * 4);
    int*   cnt     = (int*)alloc((size_t)N * 4);
    int*   rowstart= (int*)alloc((size_t)N * 4);
    int*   srclist = (int*)alloc((size_t)Etot * 4);
    int*   bucketSize   = (int*)alloc(520 * 4);
    int*   bucketStart  = (int*)alloc(520 * 4);
    int*   bucketCursor = (int*)alloc(520 * 4);
    // pairs (13.6MB) aliased over xl2b+xr2 (19.2MB contiguous, dead during CSR build)
    int2*  pairs   = (int2*)xl2b;

    int nChunks = (Etot + CHUNK - 1) / CHUNK;

    // ---- CSR build (bucketed counting sort) ----
    zeroBuckets<<<2, 256, 0, stream>>>(bucketSize, BK);
    bucketHist<<<nChunks, 256, 0, stream>>>(ei, Eorig, Etot, bucketSize, BK);
    bucketScan<<<1, 256, 0, stream>>>(bucketSize, bucketStart, bucketCursor, BK, Etot);
    bucketScatter<<<nChunks, 256, 0, stream>>>(ei, Eorig, Etot, bucketCursor, pairs, BK);
    bucketCSR<<<BK, 256, 0, stream>>>(pairs, bucketStart, rowstart, cnt, srclist, N);

    // ---- layer 1 ----
    transform1<<<(N + 63) / 64, 256, 0, stream>>>(x, W1l, b1l, W1r, b1r, xl1b, xr1, N);
    fusedAggB<HID><<<(N + 3) / 4, 256, 0, stream>>>(xl1b, xr1, att1, rowstart, cnt,
                                                    srclist, bias1, h, N);

    // ---- layer 2 ----
    transform2<<<(N + 127) / 128, 256, 0, stream>>>(h, W2l, b2l, W2r, b2r, xl2b, xr2, N);
    fusedAggB<NCLS><<<(N + 3) / 4, 256, 0, stream>>>(xl2b, xr2, att2, rowstart, cnt,
                                                     srclist, bias2, out, N);
}

// Round 13
// 319.443 us; speedup vs baseline: 1.1019x; 1.1019x over previous
//
#include <hip/hip_runtime.h>
#include <math.h>

#define F_IN 128
#define HID 64
#define NCLS 32
#define NEG 0.2f
#define NBKT 256          // nodes per bucket (dst >> 8)
#define CHUNK 8192        // edges per block in bucket passes

using bf8 = __attribute__((ext_vector_type(8))) short;   // 8 bf16 (4 VGPRs)
using f4v = __attribute__((ext_vector_type(4))) float;   // MFMA acc

__device__ __forceinline__ void f4fma(float4& a, float s, const float4& w) {
    a.x = fmaf(s, w.x, a.x);
    a.y = fmaf(s, w.y, a.y);
    a.z = fmaf(s, w.z, a.z);
    a.w = fmaf(s, w.w, a.w);
}
// float -> bf16 (round to nearest even)
__device__ __forceinline__ unsigned short f2bf(float f) {
    unsigned u = __float_as_uint(f);
    return (unsigned short)((u + 0x7FFFu + ((u >> 16) & 1u)) >> 16);
}

// =====================  CSR build: bucketed counting sort  =====================

__global__ __launch_bounds__(256) void zeroBuckets(int* __restrict__ bucketSize, int BK) {
    int i = blockIdx.x * 256 + threadIdx.x;
    if (i < BK) bucketSize[i] = 0;
}

__global__ __launch_bounds__(256) void bucketHist(const int* __restrict__ ei,
                                                  int Eorig, int Etot,
                                                  int* __restrict__ bucketSize, int BK) {
    __shared__ int h[512];
    int t = threadIdx.x;
    for (int j = t; j < BK; j += 256) h[j] = 0;
    __syncthreads();
    int base = blockIdx.x * CHUNK;
    int end = base + CHUNK < Etot ? base + CHUNK : Etot;
    for (int i = base + t; i < end; i += 256) {
        int dst = i < Eorig ? ei[Eorig + i] : i - Eorig;
        atomicAdd(&h[dst >> 8], 1);
    }
    __syncthreads();
    for (int j = t; j < BK; j += 256)
        if (h[j]) atomicAdd(&bucketSize[j], h[j]);
}

__global__ __launch_bounds__(256) void bucketScan(const int* __restrict__ bucketSize,
                                                  int* __restrict__ bucketStart,
                                                  int* __restrict__ bucketCursor,
                                                  int BK, int Etot) {
    __shared__ int sd[256];
    int t = threadIdx.x;
    int v0 = (2 * t     < BK) ? bucketSize[2 * t]     : 0;
    int v1 = (2 * t + 1 < BK) ? bucketSize[2 * t + 1] : 0;
    int ts = v0 + v1;
    sd[t] = ts;
    __syncthreads();
    for (int off = 1; off < 256; off <<= 1) {
        int x = (t >= off) ? sd[t - off] : 0;
        __syncthreads();
        sd[t] += x;
        __syncthreads();
    }
    int excl = sd[t] - ts;
    if (2 * t < BK)     { bucketStart[2 * t] = excl;          bucketCursor[2 * t] = excl; }
    if (2 * t + 1 < BK) { bucketStart[2 * t + 1] = excl + v0; bucketCursor[2 * t + 1] = excl + v0; }
    if (t == 255) bucketStart[BK] = Etot;
}

__global__ __launch_bounds__(256) void bucketScatter(const int* __restrict__ ei,
                                                     int Eorig, int Etot,
                                                     int* __restrict__ bucketCursor,
                                                     int2* __restrict__ pairs, int BK) {
    __shared__ int h[512], lbase[512], hcur[512];
    int t = threadIdx.x;
    for (int j = t; j < BK; j += 256) { h[j] = 0; hcur[j] = 0; }
    __syncthreads();
    int base = blockIdx.x * CHUNK;
    int end = base + CHUNK < Etot ? base + CHUNK : Etot;
    for (int i = base + t; i < end; i += 256) {
        int dst = i < Eorig ? ei[Eorig + i] : i - Eorig;
        atomicAdd(&h[dst >> 8], 1);
    }
    __syncthreads();
    for (int j = t; j < BK; j += 256)
        lbase[j] = h[j] ? atomicAdd(&bucketCursor[j], h[j]) : 0;
    __syncthreads();
    for (int i = base + t; i < end; i += 256) {
        int src, dst;
        if (i < Eorig) { src = ei[i]; dst = ei[Eorig + i]; }
        else           { src = dst = i - Eorig; }
        int b = dst >> 8;
        int off = atomicAdd(&hcur[b], 1);
        pairs[lbase[b] + off] = make_int2(src, dst);
    }
}

__global__ __launch_bounds__(256) void bucketCSR(const int2* __restrict__ pairs,
                                                 const int* __restrict__ bucketStart,
                                                 int* __restrict__ rowstart,
                                                 int* __restrict__ cnt,
                                                 int* __restrict__ srclist, int N) {
    __shared__ int c[256], cur[256];
    int t = threadIdx.x;
    int b = blockIdx.x;
    int lo = b * NBKT;
    int eb = bucketStart[b], ee = bucketStart[b + 1];
    c[t] = 0;
    __syncthreads();
    for (int i = eb + t; i < ee; i += 256)
        atomicAdd(&c[pairs[i].y - lo], 1);
    __syncthreads();
    cur[t] = c[t];
    __syncthreads();
    for (int off = 1; off < 256; off <<= 1) {
        int x = (t >= off) ? cur[t - off] : 0;
        __syncthreads();
        cur[t] += x;
        __syncthreads();
    }
    int excl = cur[t] - c[t];
    int node = lo + t;
    if (node < N) { rowstart[node] = eb + excl; cnt[node] = c[t]; }
    __syncthreads();
    cur[t] = excl;
    __syncthreads();
    for (int i = eb + t; i < ee; i += 256) {
        int2 pr = pairs[i];
        int pos = atomicAdd(&cur[pr.y - lo], 1);
        srclist[eb + pos] = pr.x;
    }
}

// =====================  W1 frag prep (once per call)  =====================
// Packs W1l/W1r into MFMA B-frag-ordered bf16: entry e = ((mat*4+ct)*4+kt)*64+lane,
// element j = W[kt*32 + (lane>>4)*8 + j][ct*16 + (lane&15)].  2048 x 16B = 32KB.
__global__ __launch_bounds__(256) void prepW(const float* __restrict__ Wl,
                                             const float* __restrict__ Wr,
                                             uint4* __restrict__ wfrag) {
    int e = blockIdx.x * 256 + threadIdx.x;
    if (e >= 2048) return;
    int lane = e & 63;
    int kt = (e >> 6) & 3;
    int ct = (e >> 8) & 3;
    int mat = e >> 10;
    const float* W = mat ? Wr : Wl;
    int k0 = kt * 32 + (lane >> 4) * 8;
    int c = ct * 16 + (lane & 15);
    unsigned short h[8];
#pragma unroll
    for (int j = 0; j < 8; j++) h[j] = f2bf(W[(k0 + j) * HID + c]);
    wfrag[e] = *(uint4*)h;
}

// =====================  transform1: MFMA bf16 (math ~free)  =====================
// 4 waves x 16 nodes/wave. A (x rows) packed bf16 inline; B from LDS (frag-ordered).
// D layout (verified m89): ch = ct*16 + (lane&15), node = quad*4 + reg.
// xl emitted bf16-packed (gather table), xr fp32.
__global__ __launch_bounds__(256) void transform1(const float* __restrict__ x,
                                                  const uint4* __restrict__ wfrag,
                                                  const float* __restrict__ bl,
                                                  const float* __restrict__ br,
                                                  unsigned short* __restrict__ xlb,
                                                  float* __restrict__ xr, int N) {
    __shared__ uint4 sw[2048];   // 32KB frag-ordered W (both matrices)
    int t = threadIdx.x;
#pragma unroll
    for (int j = 0; j < 8; j++) sw[t + j * 256] = wfrag[t + j * 256];
    __syncthreads();

    int w = t >> 6, lane = t & 63;
    int nb = blockIdx.x * 64 + w * 16;
    int m = lane & 15, quad = lane >> 4;

    // ---- A-frags: node = nb+m, k = kt*32 + quad*8 + j ----
    int arow = nb + m; if (arow >= N) arow = N - 1;
    const float* xrow = x + (size_t)arow * F_IN + quad * 8;
    bf8 afr[4];
#pragma unroll
    for (int kt = 0; kt < 4; kt++) {
        float4 lo = *(const float4*)(xrow + kt * 32);
        float4 hi = *(const float4*)(xrow + kt * 32 + 4);
        unsigned short hh[8];
        hh[0] = f2bf(lo.x); hh[1] = f2bf(lo.y); hh[2] = f2bf(lo.z); hh[3] = f2bf(lo.w);
        hh[4] = f2bf(hi.x); hh[5] = f2bf(hi.y); hh[6] = f2bf(hi.z); hh[7] = f2bf(hi.w);
        afr[kt] = *(bf8*)hh;
    }

    // ---- MFMA accumulate + store ----
#pragma unroll
    for (int mat = 0; mat < 2; mat++) {
        const float* bias = mat ? br : bl;
#pragma unroll
        for (int ct = 0; ct < 4; ct++) {
            f4v acc = {0.f, 0.f, 0.f, 0.f};
#pragma unroll
            for (int kt = 0; kt < 4; kt++) {
                bf8 bfr = *(bf8*)&sw[((mat * 4 + ct) * 4 + kt) * 64 + lane];
                acc = __builtin_amdgcn_mfma_f32_16x16x32_bf16(afr[kt], bfr, acc, 0, 0, 0);
            }
            int ch = ct * 16 + m;
            float bv = bias[ch];
#pragma unroll
            for (int reg = 0; reg < 4; reg++) {
                int node = nb + quad * 4 + reg;
                if (node < N) {
                    float o = acc[reg] + bv;
                    if (mat) xr[(size_t)node * HID + ch] = o;
                    else     xlb[(size_t)node * HID + ch] = f2bf(o);
                }
            }
        }
    }
}

// transform2: fp32 (accuracy hedge). xl emitted bf16-packed, xr fp32. ReLU fused.
__global__ __launch_bounds__(256) void transform2(const float* __restrict__ h,
                                                  const float* __restrict__ Wl,
                                                  const float* __restrict__ bl,
                                                  const float* __restrict__ Wr,
                                                  const float* __restrict__ br,
                                                  unsigned short* __restrict__ xlb,
                                                  float* __restrict__ xr, int N) {
    __shared__ float sWl[HID * NCLS];
    __shared__ float sWr[HID * NCLS];
    __shared__ float sx[128][68];
    int t = threadIdx.x;
    int nb = blockIdx.x * 128;

#pragma unroll
    for (int j = 0; j < 2; j++) {
        int f = t + j * 256;
        ((float4*)sWl)[f] = ((const float4*)Wl)[f];
        ((float4*)sWr)[f] = ((const float4*)Wr)[f];
    }
    int maxf = (N - nb) * 16;
#pragma unroll
    for (int j = 0; j < 8; j++) {
        int f = t + j * 256;
        int node = f >> 4, kc = f & 15;
        float4 v = {0.f, 0.f, 0.f, 0.f};
        if (f < maxf) v = ((const float4*)(h + (size_t)nb * HID))[f];
        v.x = fmaxf(v.x, 0.f);
        v.y = fmaxf(v.y, 0.f);
        v.z = fmaxf(v.z, 0.f);
        v.w = fmaxf(v.w, 0.f);
        *(float4*)&sx[node][kc * 4] = v;
    }
    __syncthreads();

    int c4 = (t & 7) * 4;
    int slot = t >> 3;
    float4 bl4 = *(const float4*)(bl + c4);
    float4 br4 = *(const float4*)(br + c4);
    float4 accl[4] = {bl4, bl4, bl4, bl4};
    float4 accr[4] = {br4, br4, br4, br4};

#pragma unroll 4
    for (int k4 = 0; k4 < HID / 4; k4++) {
        int k = k4 * 4;
        float4 wl0 = *(const float4*)&sWl[(k + 0) * NCLS + c4];
        float4 wl1 = *(const float4*)&sWl[(k + 1) * NCLS + c4];
        float4 wl2 = *(const float4*)&sWl[(k + 2) * NCLS + c4];
        float4 wl3 = *(const float4*)&sWl[(k + 3) * NCLS + c4];
        float4 wr0 = *(const float4*)&sWr[(k + 0) * NCLS + c4];
        float4 wr1 = *(const float4*)&sWr[(k + 1) * NCLS + c4];
        float4 wr2 = *(const float4*)&sWr[(k + 2) * NCLS + c4];
        float4 wr3 = *(const float4*)&sWr[(k + 3) * NCLS + c4];
#pragma unroll
        for (int j = 0; j < 4; j++) {
            float4 xv = *(const float4*)&sx[slot + j * 32][k];
            f4fma(accl[j], xv.x, wl0); f4fma(accr[j], xv.x, wr0);
            f4fma(accl[j], xv.y, wl1); f4fma(accr[j], xv.y, wr1);
            f4fma(accl[j], xv.z, wl2); f4fma(accr[j], xv.z, wr2);
            f4fma(accl[j], xv.w, wl3); f4fma(accr[j], xv.w, wr3);
        }
    }
#pragma unroll
    for (int j = 0; j < 4; j++) {
        int g = nb + slot + j * 32;
        if (g < N) {
            ushort4 o;
            o.x = f2bf(accl[j].x); o.y = f2bf(accl[j].y);
            o.z = f2bf(accl[j].z); o.w = f2bf(accl[j].w);
            *(ushort4*)(xlb + (size_t)g * NCLS + c4) = o;
            *(float4*)(xr + (size_t)g * NCLS + c4) = accr[j];
        }
    }
}

// =====================  fused softmax aggregation v6 (unroll 4)  =====================
template <int C>
__global__ __launch_bounds__(256) void fusedAggB(const unsigned short* __restrict__ xlb,
                                                 const float* __restrict__ xr,
                                                 const float* __restrict__ att,
                                                 const int* __restrict__ rowstart,
                                                 const int* __restrict__ cnt,
                                                 const int* __restrict__ srclist,
                                                 const float* __restrict__ bias,
                                                 float* __restrict__ out, int N) {
    const int LPQ = C / 8;          // lanes per edge (8 or 4)
    const int SLOTS = 64 / LPQ;     // edges per batch (8 or 16)
    int wid = threadIdx.x >> 6;
    int lane = threadIdx.x & 63;
    int n = blockIdx.x * 4 + wid;
    if (n >= N) return;

    int slot = lane / LPQ;
    int pos = lane % LPQ;
    int c8 = pos * 8;

    float xr8[8], at8[8];
    *(float4*)&xr8[0] = *(const float4*)(xr + (size_t)n * C + c8);
    *(float4*)&xr8[4] = *(const float4*)(xr + (size_t)n * C + c8 + 4);
    *(float4*)&at8[0] = *(const float4*)(att + c8);
    *(float4*)&at8[4] = *(const float4*)(att + c8 + 4);

    int row = rowstart[n];
    int deg = cnt[n];

    float s = 0.f;
    float acc[8] = {0.f, 0.f, 0.f, 0.f, 0.f, 0.f, 0.f, 0.f};

    for (int cb = 0; cb < deg; cb += 64) {
        int len = deg - cb; if (len > 64) len = 64;
        int li = lane < len ? lane : len - 1;
        int srcreg = srclist[row + cb + li];
        int nbatch = (len + SLOTS - 1) / SLOTS;
#pragma unroll 4
        for (int b = 0; b < nbatch; b++) {
            int eidx = b * SLOTS + slot;
            int src = __shfl(srcreg, eidx, 64);
            uint4 q = *(const uint4*)(xlb + (size_t)src * C + c8);  // 8 bf16
            float v[8];
            v[0] = __uint_as_float(q.x << 16);
            v[1] = __uint_as_float(q.x & 0xffff0000u);
            v[2] = __uint_as_float(q.y << 16);
            v[3] = __uint_as_float(q.y & 0xffff0000u);
            v[4] = __uint_as_float(q.z << 16);
            v[5] = __uint_as_float(q.z & 0xffff0000u);
            v[6] = __uint_as_float(q.w << 16);
            v[7] = __uint_as_float(q.w & 0xffff0000u);
            float p = 0.f;
#pragma unroll
            for (int c = 0; c < 8; c++) {
                float u = v[c] + xr8[c];
                u = fmaxf(u, NEG * u);           // leaky_relu
                p = fmaf(u, at8[c], p);
            }
#pragma unroll
            for (int o = 1; o < LPQ; o <<= 1) p += __shfl_xor(p, o, 64);
            float w = (eidx < len) ? __expf(p) : 0.f;
            s += w;
#pragma unroll
            for (int c = 0; c < 8; c++) acc[c] = fmaf(w, v[c], acc[c]);
        }
    }
#pragma unroll
    for (int o = LPQ; o < 64; o <<= 1) {
#pragma unroll
        for (int c = 0; c < 8; c++) acc[c] += __shfl_xor(acc[c], o, 64);
        s += __shfl_xor(s, o, 64);
    }
    if (lane < LPQ) {
        float bi8[8];
        *(float4*)&bi8[0] = *(const float4*)(bias + c8);
        *(float4*)&bi8[4] = *(const float4*)(bias + c8 + 4);
        float inv = 1.f / (s + 1e-16f);
        float o8[8];
#pragma unroll
        for (int c = 0; c < 8; c++) o8[c] = acc[c] * inv + bi8[c];
        *(float4*)(out + (size_t)n * C + c8)     = *(float4*)&o8[0];
        *(float4*)(out + (size_t)n * C + c8 + 4) = *(float4*)&o8[4];
    }
}

extern "C" void kernel_launch(void* const* d_in, const int* in_sizes, int n_in,
                              void* d_out, int out_size, void* d_ws, size_t ws_size,
                              hipStream_t stream) {
    const float* x     = (const float*)d_in[0];
    const int*   ei    = (const int*)d_in[1];
    const float* W1l   = (const float*)d_in[2];
    const float* b1l   = (const float*)d_in[3];
    const float* W1r   = (const float*)d_in[4];
    const float* b1r   = (const float*)d_in[5];
    const float* att1  = (const float*)d_in[6];
    const float* bias1 = (const float*)d_in[7];
    const float* W2l   = (const float*)d_in[8];
    const float* b2l   = (const float*)d_in[9];
    const float* W2r   = (const float*)d_in[10];
    const float* b2r   = (const float*)d_in[11];
    const float* att2  = (const float*)d_in[12];
    const float* bias2 = (const float*)d_in[13];
    float* out = (float*)d_out;

    int N     = in_sizes[0] / F_IN;   // 100000
    int Eorig = in_sizes[1] / 2;      // 1600000
    int Etot  = Eorig + N;
    int BK    = (N + NBKT - 1) / NBKT;   // 391 buckets (<=512)

    char* p = (char*)d_ws;
    auto alloc = [&](size_t bytes) { void* r = (void*)p; p += (bytes + 255) & ~(size_t)255; return r; };
    unsigned short* xl1b = (unsigned short*)alloc((size_t)N * HID * 2);   // bf16 table L1
    float* xr1     = (float*)alloc((size_t)N * HID * 4);
    float* h       = (float*)alloc((size_t)N * HID * 4);
    unsigned short* xl2b = (unsigned short*)alloc((size_t)N * NCLS * 2);  // bf16 table L2
    float* xr2     = (float*)alloc((size_t)N * NCLS * 4);
    int*   cnt     = (int*)alloc((size_t)N * 4);
    int*   rowstart= (int*)alloc((size_t)N * 4);
    int*   srclist = (int*)alloc((size_t)Etot * 4);
    uint4* wfrag   = (uint4*)alloc(2048 * 16);   // frag-ordered bf16 W1
    int*   bucketSize   = (int*)alloc(520 * 4);
    int*   bucketStart  = (int*)alloc(520 * 4);
    int*   bucketCursor = (int*)alloc(520 * 4);
    // pairs (13.6MB) aliased over xl2b+xr2 (19.2MB contiguous, dead during CSR build)
    int2*  pairs   = (int2*)xl2b;

    int nChunks = (Etot + CHUNK - 1) / CHUNK;

    // ---- CSR build (bucketed counting sort) ----
    zeroBuckets<<<2, 256, 0, stream>>>(bucketSize, BK);
    bucketHist<<<nChunks, 256, 0, stream>>>(ei, Eorig, Etot, bucketSize, BK);
    bucketScan<<<1, 256, 0, stream>>>(bucketSize, bucketStart, bucketCursor, BK, Etot);
    bucketScatter<<<nChunks, 256, 0, stream>>>(ei, Eorig, Etot, bucketCursor, pairs, BK);
    bucketCSR<<<BK, 256, 0, stream>>>(pairs, bucketStart, rowstart, cnt, srclist, N);

    // ---- layer 1 ----
    prepW<<<8, 256, 0, stream>>>(W1l, W1r, wfrag);
    transform1<<<(N + 63) / 64, 256, 0, stream>>>(x, wfrag, b1l, b1r, xl1b, xr1, N);
    fusedAggB<HID><<<(N + 3) / 4, 256, 0, stream>>>(xl1b, xr1, att1, rowstart, cnt,
                                                    srclist, bias1, h, N);

    // ---- layer 2 ----
    transform2<<<(N + 127) / 128, 256, 0, stream>>>(h, W2l, b2l, W2r, b2r, xl2b, xr2, N);
    fusedAggB<NCLS><<<(N + 3) / 4, 256, 0, stream>>>(xl2b, xr2, att2, rowstart, cnt,
                                                     srclist, bias2, out, N);
}